// Round 1
// 113.929 us; speedup vs baseline: 1.0190x; 1.0190x over previous
//
#include <hip/hip_runtime.h>
#include <math.h>

#define Bn 16
#define Ln 2048
#define Gn 8
#define Pn 8
#define Kn 64
#define CLAMP_V 15.0f

#define BPB 32              // blocks per batch
#define NTH 512             // threads per block = 8 waves
#define NWV (NTH / 64)      // 8 waves
#define LPB (Ln / BPB)      // 64 l's per block
#define LPW (LPB / NWV)     // 8 l's per wave
#define PK  (Pn * Kn)

// d_ws: part[Gn][Bn][BPB][Pn] qwords = {MAGIC(g)<<32 | f32 partial}.
// Harness 0xAA poison never matches a tag -> tagged partial IS the arrival
// signal; no init pass, no counters (round-10-proven protocol).
#define MAGIC(g) (0x5EED0000u | (unsigned)(g))

typedef unsigned long long ull;

// wave64 sum via DPP (VALU pipe, no LDS). Total lands in lane 63.
__device__ __forceinline__ float wave_sum64(float x) {
#define DPP_ADD(ctrl) \
    x += __int_as_float(__builtin_amdgcn_update_dpp(0, __float_as_int(x), ctrl, 0xf, 0xf, true))
    DPP_ADD(0x111);  // row_shr:1
    DPP_ADD(0x112);  // row_shr:2
    DPP_ADD(0x114);  // row_shr:4
    DPP_ADD(0x118);  // row_shr:8
    DPP_ADD(0x142);  // row_bcast:15
    DPP_ADD(0x143);  // row_bcast:31
#undef DPP_ADD
    return x;
}

template <int IMM>
__device__ __forceinline__ float swz_xor(float v) {
    return v + __int_as_float(__builtin_amdgcn_ds_swizzle(__float_as_int(v), IMM));
}
__device__ __forceinline__ ull ld_rlx64(const ull* p) {
    return __hip_atomic_load(p, __ATOMIC_RELAXED, __HIP_MEMORY_SCOPE_AGENT);
}
__device__ __forceinline__ void st_rlx64(ull* p, ull v) {
    __hip_atomic_store(p, v, __ATOMIC_RELAXED, __HIP_MEMORY_SCOPE_AGENT);
}

// ---------------------------------------------------------------------------
// r18: VOP3P packed-FP32 compute. Structure identical to the round-14 best
// (63.9us kernel): tagged-qword publish/poll sync (r10) + dn-sharing via
// ds_bpermute (r14). THIS round packs the issue-bound inner loop onto the
// dual-FP32 VOP3P pipe (v_pk_add/mul/fma_f32):
//   - dp/dn distances computed as one float2 norm ({pred, nat} lanes):
//     3 pk_sub + pk_mul + 2 pk_fma (+2 scalar sqrt) vs 12 scalar slots.
//   - p-loop processed 2 perms/step: 2 bperm + pk_sub + pk_mul + 2 v_min +
//     pk_add = 5 VALU slots per 2p vs 8.
// Expected: inner-loop VALU issue -35%; kernel ~64 -> ~57us if the compute
// phase is issue-bound (VALUBusy 42% overall ~= ~90% during compute).
// Outputs are argmin-selected gathers, so ulp reassociation keeps absmax 0.
// Attempts that FAILED to beat the r14 structure (all reverted):
//   r11 speculative cross-group compute (spills + longer serial chain)
//   r12 anti-phase stagger kick (no overlap materialized)
//   r15 BPB 32->16 skew-width cut (neutral -> skew not width-dominated)
//   r16 dual-batch interleave (max-of-64 skew + cross-chain coupling)
//   r17 last-arriver publish + prefetch/patch 1-barrier (per-wave overhead)
// Remaining budget: ~27us VALU issue + ~9us LDS-pipe bperm + ~28us
// publish->observe chain (8 serial coherence round trips inherent to the
// scan dependency) + ~52us harness launch overhead outside the kernel.
// ---------------------------------------------------------------------------
__global__ __launch_bounds__(NTH, 2) void fused_kernel(
    const float* __restrict__ xpred, const float* __restrict__ xnat,
    const int* __restrict__ mask_in, const int* __restrict__ autom,
    float* __restrict__ out_x, float* __restrict__ out_m,
    ull* __restrict__ part) {

    const int tid  = threadIdx.x;
    const int lane = tid & 63;       // k = base position
    const int wv   = tid >> 6;       // wave 0..7
    const int b    = blockIdx.x >> 5;         // batch
    const int c    = blockIdx.x & (BPB - 1);  // chunk within batch

    __shared__ float4         s_all[Ln];      // 32KB: whole-batch x_nat rows
    __shared__ unsigned short s_idx[Ln];      // 4KB: private permutation
    __shared__ unsigned char  s_inv[2][Ln];   // 4KB: node -> base position
    __shared__ float4         s_xp[LPB];      // 1KB: x_pred cols, this block
    __shared__ float          s_part[NWV][Pn];

    const float* xpb = xpred + (size_t)b * Ln * 3;
    const float* xnb = xnat  + (size_t)b * Ln * 3;

    // ---- prologue ----
    for (int l = tid; l < Ln; l += NTH) {
        s_idx[l] = (unsigned short)l;
        s_all[l] = make_float4(xnb[l * 3 + 0], xnb[l * 3 + 1], xnb[l * 3 + 2], 0.0f);
    }
    if (wv == 0) {
        const int l = c * LPB + lane;
        s_xp[lane] = make_float4(xpb[l * 3 + 0], xpb[l * 3 + 1], xpb[l * 3 + 2], 0.0f);
    } else if (wv == 2) {
        s_inv[0][autom[lane]] = (unsigned char)lane;   // group-0 inverse map
    }
    int   a0k = autom[lane];                 // group-0 base node of this lane
    float px = xpb[a0k * 3 + 0], py = xpb[a0k * 3 + 1], pz = xpb[a0k * 3 + 2];
    __syncthreads();

    #pragma unroll 1
    for (int g = 0; g < Gn; g++) {
        const int* ag  = autom + g * PK;
        const int* ag1 = autom + (g + 1) * PK;   // only read when g<7
        const int  cur = g & 1, nxt = cur ^ 1;
        ull* pg = part + (size_t)(g * Bn + b) * (BPB * Pn);

        // ---- per-group lane constants (post-update-(g-1) map) ----
        const float4 nk = s_all[s_idx[a0k]];     // native point of base pos k
        // packed {pred, nat} center, feeds the dual-FP32 pipe
        const float2 cxp = make_float2(px, nk.x);
        const float2 cyp = make_float2(py, nk.y);
        const float2 czp = make_float2(pz, nk.z);
        int sig[Pn];                             // bpermute byte addresses
        #pragma unroll
        for (int p = 0; p < Pn; p++)
            sig[p] = 4 * (int)s_inv[cur][ag[p * Kn + lane]];
        unsigned short jl[LPW];                  // hoisted column row-ids
        #pragma unroll
        for (int i = 0; i < LPW; i++)
            jl[i] = s_idx[c * LPB + wv * LPW + i];

        float2 acc2[Pn / 2];                     // .x = p even, .y = p odd
        #pragma unroll
        for (int h = 0; h < Pn / 2; h++) acc2[h] = make_float2(0.0f, 0.0f);

        // ---- compute: dn shared across the 8 perms via bpermute ----
        #pragma unroll 2
        for (int i = 0; i < LPW; i++) {
            const int il = wv * LPW + i;
            const int l  = c * LPB + il;
            if (__ballot(a0k == l)) continue;    // colmask: l in base set (rare)

            const float4 q = s_xp[il];
            const float4 m = s_all[jl[i]];
            // packed dual distance: lane0 = pred-dist, lane1 = nat-dist
            const float2 ux = cxp - make_float2(q.x, m.x);
            const float2 uy = cyp - make_float2(q.y, m.y);
            const float2 uz = czp - make_float2(q.z, m.z);
            const float2 ss = ux * ux + uy * uy + uz * uz;
            const float dp = __builtin_amdgcn_sqrtf(ss.x);
            const float dn = __builtin_amdgcn_sqrtf(ss.y);
            const int   dn_i = __float_as_int(dn);
            const float2 dp2 = make_float2(dp, dp);

            #pragma unroll
            for (int h = 0; h < Pn / 2; h++) {
                const float2 dns = make_float2(
                    __int_as_float(__builtin_amdgcn_ds_bpermute(sig[2 * h],     dn_i)),
                    __int_as_float(__builtin_amdgcn_ds_bpermute(sig[2 * h + 1], dn_i)));
                const float2 e  = dp2 - dns;
                const float2 sq = e * e;
                acc2[h] += make_float2(fminf(sq.x, CLAMP_V), fminf(sq.y, CLAMP_V));
            }
        }

        // ---- wave reduce (DPP, VALU pipe) ----
        #pragma unroll
        for (int h = 0; h < Pn / 2; h++) {
            const float vx = wave_sum64(acc2[h].x);
            const float vy = wave_sum64(acc2[h].y);
            if (lane == 63) {
                s_part[wv][2 * h]     = vx;
                s_part[wv][2 * h + 1] = vy;
            }
        }
        __syncthreads();   // (A) s_part complete; compute done block-wide

        // ---- wave 0: fold 8 waves x 8 p, publish tagged qwords ASAP ----
        if (wv == 0) {
            float v = s_part[lane >> 3][lane & 7];   // lane = (q<<3)|p
            v = swz_xor<0x201F>(v);                  // fold q bit0 (xor 8)
            v = swz_xor<0x401F>(v);                  // fold q bit1 (xor 16)
            v += __shfl(v, lane + 32, 64);           // fold q bit2 (cross-half)
            if (lane < 8)
                st_rlx64(&pg[c * Pn + lane],
                         ((ull)MAGIC(g) << 32) | (ull)__float_as_uint(v));
        }

        // ---- prefetch next group's static state ----
        if (g < Gn - 1) {
            a0k = ag1[lane];
            px = xpb[a0k * 3 + 0]; py = xpb[a0k * 3 + 1]; pz = xpb[a0k * 3 + 2];
            if (wv == 2) s_inv[nxt][ag1[lane]] = (unsigned char)lane;
        }

        // ---- wave 0: poll tagged qwords, reduce, argmin, update s_idx ----
        if (wv == 0) {
            const unsigned magic = MAGIC(g);
            ull q0 = 0, q1 = 0, q2 = 0, q3 = 0;
            bool r0 = false, r1 = false, r2 = false, r3 = false;
            for (;;) {
                if (!r0) { q0 = ld_rlx64(pg + lane);       r0 = (unsigned)(q0 >> 32) == magic; }
                if (!r1) { q1 = ld_rlx64(pg + lane + 64);  r1 = (unsigned)(q1 >> 32) == magic; }
                if (!r2) { q2 = ld_rlx64(pg + lane + 128); r2 = (unsigned)(q2 >> 32) == magic; }
                if (!r3) { q3 = ld_rlx64(pg + lane + 192); r3 = (unsigned)(q3 >> 32) == magic; }
                if (__ballot(!(r0 && r1 && r2 && r3)) == 0ull) break;
                __builtin_amdgcn_s_sleep(1);
            }
            float v = __uint_as_float((unsigned)q0) + __uint_as_float((unsigned)q1)
                    + __uint_as_float((unsigned)q2) + __uint_as_float((unsigned)q3);
            v = swz_xor<0x201F>(v);          // fold c bit (lane bit 3)
            v = swz_xor<0x401F>(v);          // fold c bit (lane bit 4)
            v += __shfl(v, lane + 32, 64);   // fold c bit (lane bit 5)
            // lanes 0..7 hold total drms[p = lane]; argmin uniform via shfl
            float best = __shfl(v, 0, 64);
            int   bj   = 0;
            #pragma unroll
            for (int p = 1; p < Pn; p++) {
                const float t = __shfl(v, p, 64);
                if (t < best) { best = t; bj = p; }  // strict < == argmin tie rule
            }
            // permutation update (gather then scatter, in-wave DS order)
            const unsigned short oldv = s_idx[ag[bj * Kn + lane]];
            s_idx[ag[lane]] = oldv;
        }
        __syncthreads();   // (B) s_idx + s_inv[nxt] visible for next compute
    }

    // ---- epilogue: out = x_native[idx] (from LDS), mask[idx] ----
    const int l0 = c * LPB;
    if (tid < LPB * 3) {
        const int ll = tid / 3, coord = tid % 3;
        const int l  = l0 + ll;
        const float4 v = s_all[s_idx[l]];
        out_x[((size_t)b * Ln + l) * 3 + coord] =
            (coord == 0) ? v.x : ((coord == 1) ? v.y : v.z);
    } else if (tid < LPB * 4) {
        const int l = l0 + (tid - LPB * 3);
        const int j = s_idx[l];
        out_m[(size_t)b * Ln + l] = (float)mask_in[(size_t)b * Ln + j];
    }
}

// ---------------------------------------------------------------------------
extern "C" void kernel_launch(void* const* d_in, const int* in_sizes, int n_in,
                              void* d_out, int out_size, void* d_ws, size_t ws_size,
                              hipStream_t stream) {
    const float* xpred   = (const float*)d_in[0];  // (B,L,3) f32
    const float* xnat_in = (const float*)d_in[1];  // (B,L,3) f32
    const int*   mask_in = (const int*)  d_in[2];  // (B,L) bool -> int32
    const int*   autom   = (const int*)  d_in[3];  // (G,P,K) -> int32

    float* out_x = (float*)d_out;          // (B,L,3)
    float* out_m = out_x + Bn * Ln * 3;    // (B,L) as float 0/1

    ull* part = (ull*)d_ws;                // Gn*Bn*BPB*Pn qwords (256KB)

    fused_kernel<<<Bn * BPB, NTH, 0, stream>>>(
        xpred, xnat_in, mask_in, autom, out_x, out_m, part);
}